// Round 8
// baseline (335.788 us; speedup 1.0000x reference)
//
#include <hip/hip_runtime.h>
#include <hip/hip_bf16.h>

// QuantizedLinear: out[t][o] = scale[o]*(sum_k x[t][k]*q[o][k] - zp[o]*sum_k x[t][k]) + bias[o]
// T=8, K=4096, OUT=11008. Weights int32 (int8-valued): 176 MB unique -> memory-bound.
//
// R8 theory: R1-R7 (43-49us, ~4.2 TB/s) all made each wave interleave 12-16
// strided row-streams advancing 1KB/iter (~30k short-burst streams chip-wide)
// -> DRAM row-buffer thrash. Fills (1 seq stream/wave) hit 7.2 TB/s.
// Fix: ONE wave = ONE channel = one purely sequential q stream; x comes from
// LDS so VMEM carries only q. 16 waves/block, 16 channels, one K-quarter.
//
//   grid = (11008/16) * 4 kq = 2752 blocks, 1024 threads (16 waves).
//   Stage x[8][1024] (32 KB) -> LDS; sync; wave w streams q[o= cg*16+w][kq*1024..]
//   in 4 iters x (1 int4/lane = 1024 B contiguous per instr). All 4 q loads
//   independent -> compiler hoists -> 4-deep MLP per wave, 16 streams/CU.
//   Per lane: acc[8] (8 tokens), xs[8] (x sums for zp term). 3 halving-stage
//   (masks 32,16,8) + 3 full-stage (4,2,1) butterflies -> lane l holds token
//   t=l>>3 fully reduced. lanes l&7==0 atomicAdd into out (zeroed by memset);
//   kq==0 adds bias. zp handled exactly (per-quarter correction is linear).

constexpr int K_IN  = 4096;
constexpr int N_OUT = 11008;
constexpr int KQ    = 1024;          // k-window per block
constexpr int ITERS = KQ / 256;      // 4

__global__ __launch_bounds__(1024) void qlin_kernel(
    const float* __restrict__ x,
    const int*   __restrict__ q,
    const float* __restrict__ scale,
    const int*   __restrict__ zp,
    const float* __restrict__ bias,
    float*       __restrict__ out)
{
    __shared__ float xlds[8 * KQ];   // 32 KB

    const int tid  = threadIdx.x;
    const int lane = tid & 63;
    const int w    = tid >> 6;           // 0..15 = local channel
    const int cg   = blockIdx.x >> 2;    // 0..687
    const int kq   = blockIdx.x & 3;     // K-quarter
    const int o    = cg * 16 + w;
    const int kbase = kq * KQ;

    // Stage x[0..7][kbase .. kbase+KQ) -> xlds. 2048 float4s / 1024 threads.
    {
        const float4* xg = reinterpret_cast<const float4*>(x);
        float4* xl = reinterpret_cast<float4*>(xlds);
        #pragma unroll
        for (int j = 0; j < 2; ++j) {
            const int f = tid + j * 1024;     // 0..2047
            const int t = f >> 8;             // token
            const int c = f & 255;            // float4 within token window
            xl[f] = xg[t * (K_IN / 4) + (kbase >> 2) + c];
        }
    }
    __syncthreads();

    const int* qrow = q + o * K_IN + kbase;

    float acc[8], xs[8];
    #pragma unroll
    for (int t = 0; t < 8; ++t) { acc[t] = 0.0f; xs[t] = 0.0f; }

    #pragma unroll
    for (int it = 0; it < ITERS; ++it) {
        const int k0 = it * 256 + lane * 4;

        const int4 qv = *reinterpret_cast<const int4*>(qrow + k0);
        const float q0 = (float)qv.x;
        const float q1 = (float)qv.y;
        const float q2 = (float)qv.z;
        const float q3 = (float)qv.w;

        #pragma unroll
        for (int t = 0; t < 8; ++t) {
            const float4 xv = *reinterpret_cast<const float4*>(&xlds[t * KQ + k0]);
            acc[t] += xv.x * q0 + xv.y * q1 + xv.z * q2 + xv.w * q3;
            xs[t]  += xv.x + xv.y + xv.z + xv.w;
        }
    }

    // 3 halving stages (masks 32,16,8): 8 values -> lane holds token t=l>>3,
    // summed over lane bits 5,4,3. (Same verified recursion as R2's 6-stage.)
    #pragma unroll
    for (int st = 0; st < 3; ++st) {
        const int m    = 32 >> st;
        const int half = 4 >> st;
        const bool hi  = (lane & m) != 0;
        #pragma unroll
        for (int i = 0; i < half; ++i) {
            const float a = acc[i];
            const float b = acc[i + half];
            const float sendA = hi ? a : b;
            acc[i] = (hi ? b : a) + __shfl_xor(sendA, m, 64);

            const float c0 = xs[i];
            const float d0 = xs[i + half];
            const float sendB = hi ? c0 : d0;
            xs[i] = (hi ? d0 : c0) + __shfl_xor(sendB, m, 64);
        }
    }
    // 3 full stages (masks 4,2,1): sum over lane bits 2,1,0.
    #pragma unroll
    for (int m = 4; m >= 1; m >>= 1) {
        acc[0] += __shfl_xor(acc[0], m, 64);
        xs[0]  += __shfl_xor(xs[0],  m, 64);
    }

    float val = scale[o] * (acc[0] - (float)zp[o] * xs[0]);
    if (kq == 0) val += bias[o];

    if ((lane & 7) == 0) {
        const int t = lane >> 3;
        atomicAdd(&out[t * N_OUT + o], val);
    }
}

extern "C" void kernel_launch(void* const* d_in, const int* in_sizes, int n_in,
                              void* d_out, int out_size, void* d_ws, size_t ws_size,
                              hipStream_t stream) {
    const float* x     = (const float*)d_in[0];
    const int*   q     = (const int*)  d_in[1];
    const float* scale = (const float*)d_in[2];
    const int*   zp    = (const int*)  d_in[3];
    const float* bias  = (const float*)d_in[4];
    float* out = (float*)d_out;

    hipMemsetAsync(out, 0, (size_t)out_size * sizeof(float), stream);

    const int blocks = (N_OUT / 16) * (K_IN / KQ);  // 688 * 4 = 2752
    qlin_kernel<<<blocks, 1024, 0, stream>>>(x, q, scale, zp, bias, out);
}

// Round 9
// 118.846 us; speedup vs baseline: 2.8254x; 2.8254x over previous
//
#include <hip/hip_runtime.h>
#include <hip/hip_bf16.h>

// QuantizedLinear: out[t][o] = scale[o]*(sum_k x[t][k]*q[o][k] - zp[o]*sum_k x[t][k]) + bias[o]
// T=8, K=4096, OUT=11008. Weights int32 (int8-valued): 180.4 MB unique -> memory-bound.
//
// R9 = R2 (best, 43.3us) + micro-tweaks. Ledger: R1-R8 tested occupancy, wave
// count, acc size, split-K depth, L1 windows, stream contiguity, atomics --
// all land 43-49us (~4.2 TB/s effective). Best-fit model: ~10us fixed replay
// overhead + ~4.5-5 TB/s scattered-row READ ceiling (fills' 7.2 TB/s is pure
// write; m13's 6.29 is r+w sum). R9 tweaks: q-loads issued before x-loads
// (misses first), epilogue operands prefetched pre-loop.
//
// Structure (= R2): block = 256 thr = 4 waves, same 8 output channels;
//   wave w = K-quarter w (1024 k = 4 iters x 256 k). Per iter per lane:
//   8 int4 q-loads then 4... 8 float4 x-loads (1024 B/instr, coalesced).
//   acc[64] = 8t x 8c; verified 6-stage halving butterfly -> lane l holds
//   output j=l (t=l>>3, c=l&7); waves 1-3 via LDS, wave 0 stores.
// Grid: 11008/8 = 1376 blocks x 4 waves = 5504 waves.

constexpr int K_IN  = 4096;
constexpr int N_OUT = 11008;
constexpr int KQ    = K_IN / 4;      // 1024 per wave
constexpr int ITERS = KQ / (64 * 4); // 4

__global__ __launch_bounds__(256, 4) void qlin_kernel(
    const float* __restrict__ x,
    const int*   __restrict__ q,
    const float* __restrict__ scale,
    const int*   __restrict__ zp,
    const float* __restrict__ bias,
    float*       __restrict__ out)
{
    __shared__ float partial[3][64];

    const int tid  = threadIdx.x;
    const int lane = tid & 63;
    const int w    = tid >> 6;        // wave = K-quarter 0..3
    const int obase = blockIdx.x * 8;
    const int kbase = w * KQ;

    // Epilogue operand prefetch: issue these scattered loads NOW so they
    // overlap the main loop instead of serializing at the end.
    const int  jj = lane >> 3;        // placeholder mapping; real j computed later
    const int  o_pre = obase + (lane & 7);
    const float sc_pre = scale[o_pre];
    const float zp_pre = (float)zp[o_pre];
    const float bi_pre = bias[o_pre];

    float acc[64];
    #pragma unroll
    for (int i = 0; i < 64; ++i) acc[i] = 0.0f;
    float xs[8];
    #pragma unroll
    for (int t = 0; t < 8; ++t) xs[t] = 0.0f;

    #pragma unroll 2
    for (int it = 0; it < ITERS; ++it) {
        const int k0 = kbase + it * 256 + lane * 4;

        // q first: these are the L2/HBM misses -- get them in flight early.
        int4 qv[8];
        #pragma unroll
        for (int c = 0; c < 8; ++c)
            qv[c] = *reinterpret_cast<const int4*>(&q[(obase + c) * K_IN + k0]);

        float4 xv[8];
        #pragma unroll
        for (int t = 0; t < 8; ++t)
            xv[t] = *reinterpret_cast<const float4*>(&x[t * K_IN + k0]);

        #pragma unroll
        for (int c = 0; c < 8; ++c) {
            const float q0 = (float)qv[c].x;
            const float q1 = (float)qv[c].y;
            const float q2 = (float)qv[c].z;
            const float q3 = (float)qv[c].w;
            #pragma unroll
            for (int t = 0; t < 8; ++t) {
                acc[t * 8 + c] += xv[t].x * q0 + xv[t].y * q1
                                + xv[t].z * q2 + xv[t].w * q3;
            }
        }
        #pragma unroll
        for (int t = 0; t < 8; ++t)
            xs[t] += xv[t].x + xv[t].y + xv[t].z + xv[t].w;
    }

    // Verified 6-stage halving butterfly (R2): 64 partials x 64 lanes ->
    // lane l holds fully-reduced value j=l (t=l>>3, c=l&7).
    #pragma unroll
    for (int s = 0; s < 6; ++s) {
        const int m    = 32 >> s;
        const int half = 32 >> s;
        const bool hi  = (lane & m) != 0;
        #pragma unroll
        for (int i = 0; i < half; ++i) {
            const float a = acc[i];
            const float b = acc[i + half];
            const float send = hi ? a : b;
            const float recv = __shfl_xor(send, m, 64);
            acc[i] = (hi ? b : a) + recv;
        }
    }

    // Per-token x sums over this wave's K-quarter (all lanes get all 8).
    #pragma unroll
    for (int m = 1; m <= 32; m <<= 1) {
        #pragma unroll
        for (int t = 0; t < 8; ++t)
            xs[t] += __shfl_xor(xs[t], m, 64);
    }

    const int t = lane >> 3;
    const int c = lane & 7;
    // Lane's stored channel is obase+c == o_pre for this lane (o_pre used c = lane&7).
    const float v = acc[0] - zp_pre * xs[t];

    if (w != 0)
        partial[w - 1][lane] = v;
    __syncthreads();
    if (w == 0) {
        const float total = v + partial[0][lane] + partial[1][lane] + partial[2][lane];
        out[t * N_OUT + (obase + c)] = sc_pre * total + bi_pre;
    }
    (void)jj;
}

extern "C" void kernel_launch(void* const* d_in, const int* in_sizes, int n_in,
                              void* d_out, int out_size, void* d_ws, size_t ws_size,
                              hipStream_t stream) {
    const float* x     = (const float*)d_in[0];
    const int*   q     = (const int*)  d_in[1];
    const float* scale = (const float*)d_in[2];
    const int*   zp    = (const int*)  d_in[3];
    const float* bias  = (const float*)d_in[4];
    float* out = (float*)d_out;

    const int blocks = N_OUT / 8;  // 1376
    qlin_kernel<<<blocks, 256, 0, stream>>>(x, q, scale, zp, bias, out);
}

// Round 10
// 43.409 us; speedup vs baseline: 7.7354x; 2.7378x over previous
//
#include <hip/hip_runtime.h>
#include <hip/hip_bf16.h>

// QuantizedLinear: out[t][o] = scale[o]*(sum_k x[t][k]*q[o][k] - zp[o]*sum_k x[t][k]) + bias[o]
// T=8, K=4096, OUT=11008. Weights int32 (int8-valued): 176 MB unique -> memory-bound.
//
// R10 = R2 verbatim (measured best, 43.3us). R9's regression (118.8us) was the
// __launch_bounds__(256,4) min-waves clamp: VGPR capped at 64 -> acc[64]
// spilled to scratch (WRITE_SIZE=164MB spill traffic). NO min-waves arg here.
//
// Empirical model after 9 rounds: every replay pulls ~164-176 MB of weights
// from HBM (not L3-resident: cyclic thrash, R9 FETCH=164MB) at a pure-read
// ceiling of ~4.2-4.3 TB/s -> floor ~= 42 us. Four diverse structures
// (R1/R2/R5/R6) all sit at 43-49 us; both traffic-reduction attempts
// (R7/R8) regressed. R2 is within ~3% of the modeled floor.
//
// Structure: block = 256 thr = 4 waves, same 8 output channels;
//   wave w = K-quarter w (1024 k = 4 iters x 256 k). Per iter per lane:
//   8 float4 x-loads + 8 int4 q-loads (1024 B/instr, coalesced, 16 in flight).
//   acc[64] = 8t x 8c; verified 6-stage halving butterfly -> lane l holds
//   output j=l (t=l>>3, c=l&7); waves 1-3 via LDS, wave 0 stores.
// Grid: 11008/8 = 1376 blocks x 4 waves = 5504 waves.

constexpr int K_IN  = 4096;
constexpr int N_OUT = 11008;
constexpr int KQ    = K_IN / 4;      // 1024 per wave
constexpr int ITERS = KQ / (64 * 4); // 4

__global__ __launch_bounds__(256) void qlin_kernel(
    const float* __restrict__ x,
    const int*   __restrict__ q,
    const float* __restrict__ scale,
    const int*   __restrict__ zp,
    const float* __restrict__ bias,
    float*       __restrict__ out)
{
    __shared__ float partial[3][64];

    const int tid  = threadIdx.x;
    const int lane = tid & 63;
    const int w    = tid >> 6;        // wave = K-quarter 0..3
    const int obase = blockIdx.x * 8;
    const int kbase = w * KQ;

    float acc[64];
    #pragma unroll
    for (int i = 0; i < 64; ++i) acc[i] = 0.0f;
    float xs[8];
    #pragma unroll
    for (int t = 0; t < 8; ++t) xs[t] = 0.0f;

    #pragma unroll 2
    for (int it = 0; it < ITERS; ++it) {
        const int k0 = kbase + it * 256 + lane * 4;

        float4 xv[8];
        #pragma unroll
        for (int t = 0; t < 8; ++t)
            xv[t] = *reinterpret_cast<const float4*>(&x[t * K_IN + k0]);

        int4 qv[8];
        #pragma unroll
        for (int c = 0; c < 8; ++c)
            qv[c] = *reinterpret_cast<const int4*>(&q[(obase + c) * K_IN + k0]);

        #pragma unroll
        for (int c = 0; c < 8; ++c) {
            const float q0 = (float)qv[c].x;
            const float q1 = (float)qv[c].y;
            const float q2 = (float)qv[c].z;
            const float q3 = (float)qv[c].w;
            #pragma unroll
            for (int t = 0; t < 8; ++t) {
                acc[t * 8 + c] += xv[t].x * q0 + xv[t].y * q1
                                + xv[t].z * q2 + xv[t].w * q3;
            }
        }
        #pragma unroll
        for (int t = 0; t < 8; ++t)
            xs[t] += xv[t].x + xv[t].y + xv[t].z + xv[t].w;
    }

    // Verified 6-stage halving butterfly: 64 partials x 64 lanes -> lane l
    // holds fully-reduced value j=l (t=l>>3, c=l&7).
    #pragma unroll
    for (int s = 0; s < 6; ++s) {
        const int m    = 32 >> s;
        const int half = 32 >> s;
        const bool hi  = (lane & m) != 0;
        #pragma unroll
        for (int i = 0; i < half; ++i) {
            const float a = acc[i];
            const float b = acc[i + half];
            const float send = hi ? a : b;
            const float recv = __shfl_xor(send, m, 64);
            acc[i] = (hi ? b : a) + recv;
        }
    }

    // Per-token x sums over this wave's K-quarter (all lanes get all 8).
    #pragma unroll
    for (int m = 1; m <= 32; m <<= 1) {
        #pragma unroll
        for (int t = 0; t < 8; ++t)
            xs[t] += __shfl_xor(xs[t], m, 64);
    }

    const int t = lane >> 3;
    const int c = lane & 7;
    const int o = obase + c;
    const float v = acc[0] - (float)zp[o] * xs[t];

    if (w != 0)
        partial[w - 1][lane] = v;
    __syncthreads();
    if (w == 0) {
        const float total = v + partial[0][lane] + partial[1][lane] + partial[2][lane];
        out[t * N_OUT + o] = scale[o] * total + bias[o];
    }
}

extern "C" void kernel_launch(void* const* d_in, const int* in_sizes, int n_in,
                              void* d_out, int out_size, void* d_ws, size_t ws_size,
                              hipStream_t stream) {
    const float* x     = (const float*)d_in[0];
    const int*   q     = (const int*)  d_in[1];
    const float* scale = (const float*)d_in[2];
    const int*   zp    = (const int*)  d_in[3];
    const float* bias  = (const float*)d_in[4];
    float* out = (float*)d_out;

    const int blocks = N_OUT / 8;  // 1376
    qlin_kernel<<<blocks, 256, 0, stream>>>(x, q, scale, zp, bias, out);
}